// Round 6
// baseline (173.833 us; speedup 1.0000x reference)
//
#include <hip/hip_runtime.h>
#include <math.h>

#define HIDDEN 64
#define RANGE 512         // nodes per range => one block owns a whole range
#define RSHIFT 9
#define NP 256            // partition chunks (pass-1 blocks)
#define NRMAX 256         // max ranges (N <= 131072)
#define CAP 128           // records per (range,chunk) slice; mean ~32, Poisson-safe
#define CAP_SHIFT 7
#define PACK_SHIFT 17     // src fits 17 bits (N <= 131072); local fits 9 bits

// ---------------------------------------------------------------------------
// R6: same 3-launch fused structure as R5, but the binning kernels read the
// comp records as a DENSE COALESCED STREAM (uint4 = 2 records/lane, fully
// independent iterations) with validity = pos < cnt[slice] from LDS, instead
// of R5's slice-serialized wave loop (48us, 13% occupancy, latency-bound:
// one dependent round-trip per ~32-record slice). 4x byte waste (mean fill
// 32/128) is cheap; garbage slots are skipped by the cnt check, so comp
// needs no initialization.
//   K1 k_part  : single-visit edge partition into (range,chunk) slices
//   K2 k_degw  : per-range deg bin + dinv=rsqrt(1+deg), w=dinv*x
//   K3 k_aggout: per-range agg bin over w[src]*ew + fused GRU + out head
// ---------------------------------------------------------------------------

__global__ __launch_bounds__(512)
void k_part(const int* __restrict__ dst, const int* __restrict__ src,
            const float* __restrict__ ew, uint2* __restrict__ comp,
            int* __restrict__ counts,
            const float* __restrict__ Wz, const float* __restrict__ bz,
            const float* __restrict__ Lz, const float* __restrict__ lbz,
            const float* __restrict__ Wh, const float* __restrict__ bh,
            const float* __restrict__ Lh, const float* __restrict__ lbh,
            float* __restrict__ coeff, int E, int nr) {
    __shared__ int cur[NRMAX];
    for (int i = threadIdx.x; i < nr; i += blockDim.x) cur[i] = 0;
    __syncthreads();

    const int b = blockIdx.x;
    long long e0 = (((long long)E * b) / NP) & ~3LL;
    long long e1 = (b == NP - 1) ? (long long)E
                                 : ((((long long)E * (b + 1)) / NP) & ~3LL);
    const int nvec = (int)((e1 - e0) >> 2);
    const int4*   dst4 = (const int4*)(dst + e0);
    const int4*   src4 = (const int4*)(src + e0);
    const float4* ew4  = (const float4*)(ew + e0);

    for (int i = threadIdx.x; i < nvec; i += blockDim.x) {
        int4   d = dst4[i];
        int4   s = src4[i];
        float4 t = ew4[i];
        int   dd[4] = {d.x, d.y, d.z, d.w};
        int   ss[4] = {s.x, s.y, s.z, s.w};
        float tt[4] = {t.x, t.y, t.z, t.w};
        #pragma unroll
        for (int j = 0; j < 4; ++j) {
            unsigned u = (unsigned)dd[j];
            int r = (int)(u >> RSHIFT);
            unsigned l = u & (RANGE - 1);
            int pos = atomicAdd(&cur[r], 1);
            if (pos < CAP)
                comp[(((size_t)(r * NP + b)) << CAP_SHIFT) + pos] =
                    make_uint2((l << PACK_SHIFT) | (unsigned)ss[j],
                               __float_as_uint(tt[j]));
        }
    }
    // scalar tail (last chunk only, < 4 edges)
    for (long long e = e0 + ((long long)nvec << 2) + threadIdx.x; e < e1;
         e += blockDim.x) {
        unsigned u = (unsigned)dst[e];
        int r = (int)(u >> RSHIFT);
        unsigned l = u & (RANGE - 1);
        int pos = atomicAdd(&cur[r], 1);
        if (pos < CAP)
            comp[(((size_t)(r * NP + b)) << CAP_SHIFT) + pos] =
                make_uint2((l << PACK_SHIFT) | (unsigned)src[e],
                           __float_as_uint(ew[e]));
    }
    __syncthreads();
    for (int rr = threadIdx.x; rr < nr; rr += blockDim.x)
        counts[rr * NP + b] = min(cur[rr], CAP);

    // GRU coefficient folding (H0=0 => only top 64 rows of Lz/Lh; R gate dead)
    if (b == 0 && threadIdx.x < HIDDEN) {
        int j = threadIdx.x;
        float vz = 0.f, cz = 0.f, vh = 0.f, ch = 0.f;
        for (int k = 0; k < HIDDEN; ++k) {
            float lz = Lz[k * HIDDEN + j];
            float lh = Lh[k * HIDDEN + j];
            vz += Wz[k] * lz;
            cz += bz[k] * lz;
            vh += Wh[k] * lh;
            ch += bh[k] * lh;
        }
        coeff[j]       = vz;
        coeff[64 + j]  = cz + lbz[j];
        coeff[128 + j] = vh;
        coeff[192 + j] = ch + lbh[j];
    }
}

__global__ __launch_bounds__(512)
void k_degw(const uint2* __restrict__ comp, const int* __restrict__ counts,
            const float* __restrict__ x, float* __restrict__ dinv,
            float* __restrict__ w, int N) {
    __shared__ float bins[RANGE];
    __shared__ int cnt[NP];
    const int r = blockIdx.x;
    for (int i = threadIdx.x; i < RANGE; i += blockDim.x) bins[i] = 1.0f; // +self-loop
    for (int i = threadIdx.x; i < NP; i += blockDim.x) cnt[i] = counts[r * NP + i];
    __syncthreads();

    // dense coalesced stream over all NP*CAP slots, 2 records per lane
    const uint4* base4 = (const uint4*)(comp + ((size_t)r * NP << CAP_SHIFT));
    for (int i = threadIdx.x; i < (NP << CAP_SHIFT) / 2; i += blockDim.x) {
        uint4 e = base4[i];
        int s0 = i << 1;                       // even => s0,s0+1 share a slice
        int b = s0 >> CAP_SHIFT;
        int pos = s0 & (CAP - 1);
        int n = cnt[b];
        if (pos < n)
            atomicAdd(&bins[e.x >> PACK_SHIFT], __uint_as_float(e.y));
        if (pos + 1 < n)
            atomicAdd(&bins[e.z >> PACK_SHIFT], __uint_as_float(e.w));
    }
    __syncthreads();
    const int g0 = r << RSHIFT;
    for (int i = threadIdx.x; i < RANGE; i += blockDim.x) {
        int g = g0 + i;
        if (g < N) {
            float di = rsqrtf(bins[i]);
            dinv[g] = di;
            w[g] = di * x[g];
        }
    }
}

__global__ __launch_bounds__(512)
void k_aggout(const uint2* __restrict__ comp, const int* __restrict__ counts,
              const float* __restrict__ w, const float* __restrict__ dinv,
              const float* __restrict__ coeff, const float* __restrict__ Wout,
              const float* __restrict__ bout, float* __restrict__ out, int N) {
    __shared__ float bins[RANGE];
    __shared__ int cnt[NP];
    __shared__ float cc[5 * HIDDEN + 1];
    const int r = blockIdx.x;
    for (int i = threadIdx.x; i < RANGE; i += blockDim.x) bins[i] = 0.f;
    for (int i = threadIdx.x; i < NP; i += blockDim.x) cnt[i] = counts[r * NP + i];
    if (threadIdx.x < 4 * HIDDEN) cc[threadIdx.x] = coeff[threadIdx.x];
    else if (threadIdx.x < 5 * HIDDEN) cc[threadIdx.x] = Wout[threadIdx.x - 4 * HIDDEN];
    if (threadIdx.x == 0) cc[5 * HIDDEN] = bout[0];
    __syncthreads();

    // dense coalesced stream; w[src] gathers are independent across slots
    const uint4* base4 = (const uint4*)(comp + ((size_t)r * NP << CAP_SHIFT));
    for (int i = threadIdx.x; i < (NP << CAP_SHIFT) / 2; i += blockDim.x) {
        uint4 e = base4[i];
        int s0 = i << 1;
        int b = s0 >> CAP_SHIFT;
        int pos = s0 & (CAP - 1);
        int n = cnt[b];
        if (pos < n) {
            float v = w[e.x & ((1u << PACK_SHIFT) - 1u)] * __uint_as_float(e.y);
            atomicAdd(&bins[e.x >> PACK_SHIFT], v);
        }
        if (pos + 1 < n) {
            float v = w[e.z & ((1u << PACK_SHIFT) - 1u)] * __uint_as_float(e.w);
            atomicAdd(&bins[e.z >> PACK_SHIFT], v);
        }
    }
    __syncthreads();
    const int g0 = r << RSHIFT;
    const float b0 = cc[5 * HIDDEN];
    for (int i = threadIdx.x; i < RANGE; i += blockDim.x) {
        int g = g0 + i;
        if (g < N) {
            float si = dinv[g] * (bins[i] + w[g]);   // w term = self-loop
            float acc = b0;
            #pragma unroll
            for (int j = 0; j < HIDDEN; ++j) {
                float zp = fminf(fmaxf(si * cc[j] + cc[64 + j], -30.f), 30.f);
                float hp = fminf(fmaxf(si * cc[128 + j] + cc[192 + j], -15.f), 15.f);
                float a  = __expf(2.0f * hp);               // tanh(hp)=(a-1)/(a+1)
                float t  = (a - 1.0f) / (a + 1.0f);
                float zn = 1.0f / (1.0f + __expf(zp));      // 1 - sigmoid(zp)
                float hn = zn * t;
                hn = hn > 0.0f ? hn : 0.0f;
                acc = fmaf(hn, cc[256 + j], acc);
            }
            out[g] = acc;
        }
    }
}

extern "C" void kernel_launch(void* const* d_in, const int* in_sizes, int n_in,
                              void* d_out, int out_size, void* d_ws, size_t ws_size,
                              hipStream_t stream) {
    const float* x    = (const float*)d_in[0];
    const float* ew   = (const float*)d_in[1];
    const float* Wz   = (const float*)d_in[2];
    const float* bz   = (const float*)d_in[3];
    const float* Lz   = (const float*)d_in[4];
    const float* lbz  = (const float*)d_in[5];
    // d_in[6..9] = Wr, br, Lr, lbr — dead (H0 = 0 makes the R gate unused)
    const float* Wh   = (const float*)d_in[10];
    const float* bh   = (const float*)d_in[11];
    const float* Lh   = (const float*)d_in[12];
    const float* lbh  = (const float*)d_in[13];
    const float* Wout = (const float*)d_in[14];
    const float* bout = (const float*)d_in[15];
    const int*   eidx = (const int*)d_in[16];

    const int N = in_sizes[0];          // x is [N,1]  (100000 -> src fits 17 bits)
    const int E = in_sizes[1];          // edge_weight is [E]
    const int* src = eidx;              // edge_index[0]
    const int* dst = eidx + E;          // edge_index[1]

    const int nr = (N + RANGE - 1) / RANGE;          // 196 ranges

    // Workspace (~52 MB of the 256 MiB d_ws):
    uint2* comp   = (uint2*)d_ws;                               // nr*NP*CAP
    int*   counts = (int*)(comp + ((size_t)nr * NP << CAP_SHIFT)); // nr*NP
    float* dinv   = (float*)(counts + (size_t)nr * NP);         // N
    float* w      = dinv + N;                                   // N
    float* coeff  = w + N;                                      // 4*HIDDEN

    k_part<<<NP, 512, 0, stream>>>(dst, src, ew, comp, counts,
                                   Wz, bz, Lz, lbz, Wh, bh, Lh, lbh,
                                   coeff, E, nr);
    k_degw<<<nr, 512, 0, stream>>>(comp, counts, x, dinv, w, N);
    k_aggout<<<nr, 512, 0, stream>>>(comp, counts, w, dinv, coeff, Wout, bout,
                                     (float*)d_out, N);
}

// Round 7
// 148.971 us; speedup vs baseline: 1.1669x; 1.1669x over previous
//
#include <hip/hip_runtime.h>
#include <math.h>

#define HIDDEN 64
#define RANGE 256         // nodes per range => one block owns a whole range
#define RSHIFT 8
#define NP 256            // partition chunks (pass-1 blocks)
#define NRMAX 512         // max ranges (N <= 131072)
#define CAP 48            // records per (range,chunk) slice; mean ~16, +8 sigma
#define PACK_SHIFT 17     // src fits 17 bits (N <= 131072); local fits 8 bits

// ---------------------------------------------------------------------------
// R7: R6 structure, occupancy-fixed. R6's binning kernels were latency-bound
// at 13% occupancy (196 blocks -> 60 idle CUs, ~1.5 waves/SIMD), NOT
// pattern-bound. Fix: RANGE 512->256 (392 blocks, all CUs busy, ~12 waves/CU)
// and CAP 128->48 (slot waste 4x -> 3x, 51->38.5 MB streamed).
//   K1 k_part  : single-visit edge partition into (range,chunk) slices
//   K2 k_degw  : per-range deg bin + dinv=rsqrt(1+deg), w=dinv*x
//   K3 k_aggout: per-range agg bin over w[src]*ew + fused GRU + out head
// ---------------------------------------------------------------------------

__global__ __launch_bounds__(512)
void k_part(const int* __restrict__ dst, const int* __restrict__ src,
            const float* __restrict__ ew, uint2* __restrict__ comp,
            int* __restrict__ counts,
            const float* __restrict__ Wz, const float* __restrict__ bz,
            const float* __restrict__ Lz, const float* __restrict__ lbz,
            const float* __restrict__ Wh, const float* __restrict__ bh,
            const float* __restrict__ Lh, const float* __restrict__ lbh,
            float* __restrict__ coeff, int E, int nr) {
    __shared__ int cur[NRMAX];
    for (int i = threadIdx.x; i < nr; i += blockDim.x) cur[i] = 0;
    __syncthreads();

    const int b = blockIdx.x;
    long long e0 = (((long long)E * b) / NP) & ~3LL;
    long long e1 = (b == NP - 1) ? (long long)E
                                 : ((((long long)E * (b + 1)) / NP) & ~3LL);
    const int nvec = (int)((e1 - e0) >> 2);
    const int4*   dst4 = (const int4*)(dst + e0);
    const int4*   src4 = (const int4*)(src + e0);
    const float4* ew4  = (const float4*)(ew + e0);

    for (int i = threadIdx.x; i < nvec; i += blockDim.x) {
        int4   d = dst4[i];
        int4   s = src4[i];
        float4 t = ew4[i];
        int   dd[4] = {d.x, d.y, d.z, d.w};
        int   ss[4] = {s.x, s.y, s.z, s.w};
        float tt[4] = {t.x, t.y, t.z, t.w};
        #pragma unroll
        for (int j = 0; j < 4; ++j) {
            unsigned u = (unsigned)dd[j];
            int r = (int)(u >> RSHIFT);
            unsigned l = u & (RANGE - 1);
            int pos = atomicAdd(&cur[r], 1);
            if (pos < CAP)
                comp[((size_t)(r * NP + b)) * CAP + pos] =
                    make_uint2((l << PACK_SHIFT) | (unsigned)ss[j],
                               __float_as_uint(tt[j]));
        }
    }
    // scalar tail (last chunk only, < 4 edges)
    for (long long e = e0 + ((long long)nvec << 2) + threadIdx.x; e < e1;
         e += blockDim.x) {
        unsigned u = (unsigned)dst[e];
        int r = (int)(u >> RSHIFT);
        unsigned l = u & (RANGE - 1);
        int pos = atomicAdd(&cur[r], 1);
        if (pos < CAP)
            comp[((size_t)(r * NP + b)) * CAP + pos] =
                make_uint2((l << PACK_SHIFT) | (unsigned)src[e],
                           __float_as_uint(ew[e]));
    }
    __syncthreads();
    for (int rr = threadIdx.x; rr < nr; rr += blockDim.x)
        counts[rr * NP + b] = min(cur[rr], CAP);

    // GRU coefficient folding (H0=0 => only top 64 rows of Lz/Lh; R gate dead)
    if (b == 0 && threadIdx.x < HIDDEN) {
        int j = threadIdx.x;
        float vz = 0.f, cz = 0.f, vh = 0.f, ch = 0.f;
        for (int k = 0; k < HIDDEN; ++k) {
            float lz = Lz[k * HIDDEN + j];
            float lh = Lh[k * HIDDEN + j];
            vz += Wz[k] * lz;
            cz += bz[k] * lz;
            vh += Wh[k] * lh;
            ch += bh[k] * lh;
        }
        coeff[j]       = vz;
        coeff[64 + j]  = cz + lbz[j];
        coeff[128 + j] = vh;
        coeff[192 + j] = ch + lbh[j];
    }
}

__global__ __launch_bounds__(512)
void k_degw(const uint2* __restrict__ comp, const int* __restrict__ counts,
            const float* __restrict__ x, float* __restrict__ dinv,
            float* __restrict__ w, int N) {
    __shared__ float bins[RANGE];
    __shared__ int cnt[NP];
    const int r = blockIdx.x;
    if (threadIdx.x < RANGE) bins[threadIdx.x] = 1.0f;   // +self-loop
    for (int i = threadIdx.x; i < NP; i += blockDim.x) cnt[i] = counts[r * NP + i];
    __syncthreads();

    // dense coalesced stream over all NP*CAP slots, 2 records per lane.
    // CAP is even => a uint4 pair never straddles a slice; slice base is
    // 384B (16B-aligned).
    const uint4* base4 = (const uint4*)(comp + (size_t)r * NP * CAP);
    for (int i = threadIdx.x; i < (NP * CAP) / 2; i += blockDim.x) {
        uint4 e = base4[i];
        int s0 = i << 1;
        int b = s0 / CAP;                  // magic-mul div by 48
        int pos = s0 - b * CAP;
        int n = cnt[b];
        if (pos < n)
            atomicAdd(&bins[e.x >> PACK_SHIFT], __uint_as_float(e.y));
        if (pos + 1 < n)
            atomicAdd(&bins[e.z >> PACK_SHIFT], __uint_as_float(e.w));
    }
    __syncthreads();
    const int g0 = r << RSHIFT;
    if (threadIdx.x < RANGE) {
        int g = g0 + threadIdx.x;
        if (g < N) {
            float di = rsqrtf(bins[threadIdx.x]);
            dinv[g] = di;
            w[g] = di * x[g];
        }
    }
}

__global__ __launch_bounds__(512)
void k_aggout(const uint2* __restrict__ comp, const int* __restrict__ counts,
              const float* __restrict__ w, const float* __restrict__ dinv,
              const float* __restrict__ coeff, const float* __restrict__ Wout,
              const float* __restrict__ bout, float* __restrict__ out, int N) {
    __shared__ float bins[RANGE];
    __shared__ int cnt[NP];
    __shared__ float cc[5 * HIDDEN + 1];
    const int r = blockIdx.x;
    if (threadIdx.x < RANGE) bins[threadIdx.x] = 0.f;
    for (int i = threadIdx.x; i < NP; i += blockDim.x) cnt[i] = counts[r * NP + i];
    if (threadIdx.x < 4 * HIDDEN) cc[threadIdx.x] = coeff[threadIdx.x];
    else if (threadIdx.x < 5 * HIDDEN) cc[threadIdx.x] = Wout[threadIdx.x - 4 * HIDDEN];
    if (threadIdx.x == 0) cc[5 * HIDDEN] = bout[0];
    __syncthreads();

    // dense coalesced stream; w[src] gathers independent across slots
    const uint4* base4 = (const uint4*)(comp + (size_t)r * NP * CAP);
    for (int i = threadIdx.x; i < (NP * CAP) / 2; i += blockDim.x) {
        uint4 e = base4[i];
        int s0 = i << 1;
        int b = s0 / CAP;
        int pos = s0 - b * CAP;
        int n = cnt[b];
        if (pos < n) {
            float v = w[e.x & ((1u << PACK_SHIFT) - 1u)] * __uint_as_float(e.y);
            atomicAdd(&bins[e.x >> PACK_SHIFT], v);
        }
        if (pos + 1 < n) {
            float v = w[e.z & ((1u << PACK_SHIFT) - 1u)] * __uint_as_float(e.w);
            atomicAdd(&bins[e.z >> PACK_SHIFT], v);
        }
    }
    __syncthreads();
    const int g0 = r << RSHIFT;
    const float b0 = cc[5 * HIDDEN];
    if (threadIdx.x < RANGE) {
        int g = g0 + threadIdx.x;
        if (g < N) {
            float si = dinv[g] * (bins[threadIdx.x] + w[g]);   // w term = self-loop
            float acc = b0;
            #pragma unroll
            for (int j = 0; j < HIDDEN; ++j) {
                float zp = fminf(fmaxf(si * cc[j] + cc[64 + j], -30.f), 30.f);
                float hp = fminf(fmaxf(si * cc[128 + j] + cc[192 + j], -15.f), 15.f);
                float a  = __expf(2.0f * hp);               // tanh(hp)=(a-1)/(a+1)
                float t  = (a - 1.0f) / (a + 1.0f);
                float zn = 1.0f / (1.0f + __expf(zp));      // 1 - sigmoid(zp)
                float hn = zn * t;
                hn = hn > 0.0f ? hn : 0.0f;
                acc = fmaf(hn, cc[256 + j], acc);
            }
            out[g] = acc;
        }
    }
}

extern "C" void kernel_launch(void* const* d_in, const int* in_sizes, int n_in,
                              void* d_out, int out_size, void* d_ws, size_t ws_size,
                              hipStream_t stream) {
    const float* x    = (const float*)d_in[0];
    const float* ew   = (const float*)d_in[1];
    const float* Wz   = (const float*)d_in[2];
    const float* bz   = (const float*)d_in[3];
    const float* Lz   = (const float*)d_in[4];
    const float* lbz  = (const float*)d_in[5];
    // d_in[6..9] = Wr, br, Lr, lbr — dead (H0 = 0 makes the R gate unused)
    const float* Wh   = (const float*)d_in[10];
    const float* bh   = (const float*)d_in[11];
    const float* Lh   = (const float*)d_in[12];
    const float* lbh  = (const float*)d_in[13];
    const float* Wout = (const float*)d_in[14];
    const float* bout = (const float*)d_in[15];
    const int*   eidx = (const int*)d_in[16];

    const int N = in_sizes[0];          // x is [N,1]  (100000 -> src fits 17 bits)
    const int E = in_sizes[1];          // edge_weight is [E]
    const int* src = eidx;              // edge_index[0]
    const int* dst = eidx + E;          // edge_index[1]

    const int nr = (N + RANGE - 1) / RANGE;          // 392 ranges

    // Workspace (~40 MB of the 256 MiB d_ws):
    uint2* comp   = (uint2*)d_ws;                                  // nr*NP*CAP
    int*   counts = (int*)(comp + (size_t)nr * NP * CAP);          // nr*NP
    float* dinv   = (float*)(counts + (size_t)nr * NP);            // N
    float* w      = dinv + N;                                      // N
    float* coeff  = w + N;                                         // 4*HIDDEN

    k_part<<<NP, 512, 0, stream>>>(dst, src, ew, comp, counts,
                                   Wz, bz, Lz, lbz, Wh, bh, Lh, lbh,
                                   coeff, E, nr);
    k_degw<<<nr, 512, 0, stream>>>(comp, counts, x, dinv, w, N);
    k_aggout<<<nr, 512, 0, stream>>>(comp, counts, w, dinv, coeff, Wout, bout,
                                     (float*)d_out, N);
}

// Round 8
// 148.267 us; speedup vs baseline: 1.1724x; 1.0047x over previous
//
#include <hip/hip_runtime.h>
#include <math.h>

#define HIDDEN 64
#define RANGE 256         // nodes per range => one block owns a whole range
#define RSHIFT 8
#define NP 256            // partition chunk-blocks
#define NRMAX 512         // max ranges (N <= 131072)
#define PACK_SHIFT 17     // src fits 17 bits (N <= 131072); local fits 8 bits

// ---------------------------------------------------------------------------
// R8: DENSE comp. R6/R7 counters showed the binning kernels thrashing the
// 4MiB/XCD L2 with the 3x-oversized slotted comp (FETCH 43MB + WRITE 33MB
// at ~1.5TB/s miss-path = ~38us each). Fix: two-pass k_part —
//   pass 1: LDS histogram by range; reserve dense runs via ONE global
//           atomicAdd(rcur[r], hist[r]) per (block,range) (~100K int atomics
//           on 392 counters — NOT R2's fatal 1.6M scattered fp32 atomics);
//   pass 2: re-read edges (L3-warm), scatter to comp[r*capr + base + i].
// Segments are dense; slack (capr = mean+8sigma) is never read: readers
// stream exactly rcur[r] records. comp: 38.5 -> 14.5 MB (L2-resident).
//   K1 k_part  : dense partition + GRU coeff fold
//   K2 k_degw  : per-range deg bin + dinv=rsqrt(1+deg), w=dinv*x
//   K3 k_aggout: per-range agg bin over w[src]*ew + fused GRU + out head
// ---------------------------------------------------------------------------

__global__ __launch_bounds__(512)
void k_part(const int* __restrict__ dst, const int* __restrict__ src,
            const float* __restrict__ ew, uint2* __restrict__ comp,
            int* __restrict__ rcur,
            const float* __restrict__ Wz, const float* __restrict__ bz,
            const float* __restrict__ Lz, const float* __restrict__ lbz,
            const float* __restrict__ Wh, const float* __restrict__ bh,
            const float* __restrict__ Lh, const float* __restrict__ lbh,
            float* __restrict__ coeff, int E, int nr, int capr) {
    __shared__ int hist[NRMAX];    // pass1: per-range count; pass2: running cursor
    __shared__ int lbase[NRMAX];   // global run base for this block
    for (int i = threadIdx.x; i < nr; i += blockDim.x) hist[i] = 0;
    __syncthreads();

    const int b = blockIdx.x;
    long long e0 = (((long long)E * b) / NP) & ~3LL;
    long long e1 = (b == NP - 1) ? (long long)E
                                 : ((((long long)E * (b + 1)) / NP) & ~3LL);
    const int nvec = (int)((e1 - e0) >> 2);
    const int4*   dst4 = (const int4*)(dst + e0);
    const int4*   src4 = (const int4*)(src + e0);
    const float4* ew4  = (const float4*)(ew + e0);

    // ---- pass 1: histogram by range ----
    for (int i = threadIdx.x; i < nvec; i += blockDim.x) {
        int4 d = dst4[i];
        atomicAdd(&hist[((unsigned)d.x) >> RSHIFT], 1);
        atomicAdd(&hist[((unsigned)d.y) >> RSHIFT], 1);
        atomicAdd(&hist[((unsigned)d.z) >> RSHIFT], 1);
        atomicAdd(&hist[((unsigned)d.w) >> RSHIFT], 1);
    }
    for (long long e = e0 + ((long long)nvec << 2) + threadIdx.x; e < e1;
         e += blockDim.x)
        atomicAdd(&hist[((unsigned)dst[e]) >> RSHIFT], 1);
    __syncthreads();

    // ---- reserve dense runs ----
    for (int rr = threadIdx.x; rr < nr; rr += blockDim.x)
        lbase[rr] = atomicAdd(&rcur[rr], hist[rr]);
    __syncthreads();
    for (int i = threadIdx.x; i < nr; i += blockDim.x) hist[i] = 0;
    __syncthreads();

    // ---- pass 2: scatter into dense segments ----
    for (int i = threadIdx.x; i < nvec; i += blockDim.x) {
        int4   d = dst4[i];
        int4   s = src4[i];
        float4 t = ew4[i];
        int   dd[4] = {d.x, d.y, d.z, d.w};
        int   ss[4] = {s.x, s.y, s.z, s.w};
        float tt[4] = {t.x, t.y, t.z, t.w};
        #pragma unroll
        for (int j = 0; j < 4; ++j) {
            unsigned u = (unsigned)dd[j];
            int r = (int)(u >> RSHIFT);
            unsigned l = u & (RANGE - 1);
            int pos = lbase[r] + atomicAdd(&hist[r], 1);
            if (pos < capr)
                comp[(size_t)r * capr + pos] =
                    make_uint2((l << PACK_SHIFT) | (unsigned)ss[j],
                               __float_as_uint(tt[j]));
        }
    }
    for (long long e = e0 + ((long long)nvec << 2) + threadIdx.x; e < e1;
         e += blockDim.x) {
        unsigned u = (unsigned)dst[e];
        int r = (int)(u >> RSHIFT);
        unsigned l = u & (RANGE - 1);
        int pos = lbase[r] + atomicAdd(&hist[r], 1);
        if (pos < capr)
            comp[(size_t)r * capr + pos] =
                make_uint2((l << PACK_SHIFT) | (unsigned)src[e],
                           __float_as_uint(ew[e]));
    }

    // GRU coefficient folding (H0=0 => only top 64 rows of Lz/Lh; R gate dead)
    if (b == 0 && threadIdx.x < HIDDEN) {
        int j = threadIdx.x;
        float vz = 0.f, cz = 0.f, vh = 0.f, ch = 0.f;
        for (int k = 0; k < HIDDEN; ++k) {
            float lz = Lz[k * HIDDEN + j];
            float lh = Lh[k * HIDDEN + j];
            vz += Wz[k] * lz;
            cz += bz[k] * lz;
            vh += Wh[k] * lh;
            ch += bh[k] * lh;
        }
        coeff[j]       = vz;
        coeff[64 + j]  = cz + lbz[j];
        coeff[128 + j] = vh;
        coeff[192 + j] = ch + lbh[j];
    }
}

__global__ __launch_bounds__(512)
void k_degw(const uint2* __restrict__ comp, const int* __restrict__ rcur,
            const float* __restrict__ x, float* __restrict__ dinv,
            float* __restrict__ w, int N, int capr) {
    __shared__ float bins[RANGE];
    const int r = blockIdx.x;
    if (threadIdx.x < RANGE) bins[threadIdx.x] = 1.0f;   // +self-loop
    __syncthreads();

    const int n = min(rcur[r], capr);         // exact record count, dense
    const uint4* seg4 = (const uint4*)(comp + (size_t)r * capr);
    const int nv = n >> 1;
    for (int i = threadIdx.x; i < nv; i += blockDim.x) {
        uint4 e = seg4[i];
        atomicAdd(&bins[e.x >> PACK_SHIFT], __uint_as_float(e.y));
        atomicAdd(&bins[e.z >> PACK_SHIFT], __uint_as_float(e.w));
    }
    if ((n & 1) && threadIdx.x == 0) {
        uint2 e = (comp + (size_t)r * capr)[n - 1];
        atomicAdd(&bins[e.x >> PACK_SHIFT], __uint_as_float(e.y));
    }
    __syncthreads();
    const int g0 = r << RSHIFT;
    if (threadIdx.x < RANGE) {
        int g = g0 + threadIdx.x;
        if (g < N) {
            float di = rsqrtf(bins[threadIdx.x]);
            dinv[g] = di;
            w[g] = di * x[g];
        }
    }
}

__global__ __launch_bounds__(512)
void k_aggout(const uint2* __restrict__ comp, const int* __restrict__ rcur,
              const float* __restrict__ w, const float* __restrict__ dinv,
              const float* __restrict__ coeff, const float* __restrict__ Wout,
              const float* __restrict__ bout, float* __restrict__ out,
              int N, int capr) {
    __shared__ float bins[RANGE];
    __shared__ float cc[5 * HIDDEN + 1];
    const int r = blockIdx.x;
    if (threadIdx.x < RANGE) bins[threadIdx.x] = 0.f;
    if (threadIdx.x < 4 * HIDDEN) cc[threadIdx.x] = coeff[threadIdx.x];
    else if (threadIdx.x < 5 * HIDDEN) cc[threadIdx.x] = Wout[threadIdx.x - 4 * HIDDEN];
    if (threadIdx.x == 0) cc[5 * HIDDEN] = bout[0];
    __syncthreads();

    const int n = min(rcur[r], capr);
    const uint4* seg4 = (const uint4*)(comp + (size_t)r * capr);
    const int nv = n >> 1;
    for (int i = threadIdx.x; i < nv; i += blockDim.x) {
        uint4 e = seg4[i];
        float v0 = w[e.x & ((1u << PACK_SHIFT) - 1u)] * __uint_as_float(e.y);
        atomicAdd(&bins[e.x >> PACK_SHIFT], v0);
        float v1 = w[e.z & ((1u << PACK_SHIFT) - 1u)] * __uint_as_float(e.w);
        atomicAdd(&bins[e.z >> PACK_SHIFT], v1);
    }
    if ((n & 1) && threadIdx.x == 0) {
        uint2 e = (comp + (size_t)r * capr)[n - 1];
        float v = w[e.x & ((1u << PACK_SHIFT) - 1u)] * __uint_as_float(e.y);
        atomicAdd(&bins[e.x >> PACK_SHIFT], v);
    }
    __syncthreads();
    const int g0 = r << RSHIFT;
    const float b0 = cc[5 * HIDDEN];
    if (threadIdx.x < RANGE) {
        int g = g0 + threadIdx.x;
        if (g < N) {
            float si = dinv[g] * (bins[threadIdx.x] + w[g]);   // w term = self-loop
            float acc = b0;
            #pragma unroll
            for (int j = 0; j < HIDDEN; ++j) {
                float zp = fminf(fmaxf(si * cc[j] + cc[64 + j], -30.f), 30.f);
                float hp = fminf(fmaxf(si * cc[128 + j] + cc[192 + j], -15.f), 15.f);
                float a  = __expf(2.0f * hp);               // tanh(hp)=(a-1)/(a+1)
                float t  = (a - 1.0f) / (a + 1.0f);
                float zn = 1.0f / (1.0f + __expf(zp));      // 1 - sigmoid(zp)
                float hn = zn * t;
                hn = hn > 0.0f ? hn : 0.0f;
                acc = fmaf(hn, cc[256 + j], acc);
            }
            out[g] = acc;
        }
    }
}

extern "C" void kernel_launch(void* const* d_in, const int* in_sizes, int n_in,
                              void* d_out, int out_size, void* d_ws, size_t ws_size,
                              hipStream_t stream) {
    const float* x    = (const float*)d_in[0];
    const float* ew   = (const float*)d_in[1];
    const float* Wz   = (const float*)d_in[2];
    const float* bz   = (const float*)d_in[3];
    const float* Lz   = (const float*)d_in[4];
    const float* lbz  = (const float*)d_in[5];
    // d_in[6..9] = Wr, br, Lr, lbr — dead (H0 = 0 makes the R gate unused)
    const float* Wh   = (const float*)d_in[10];
    const float* bh   = (const float*)d_in[11];
    const float* Lh   = (const float*)d_in[12];
    const float* lbh  = (const float*)d_in[13];
    const float* Wout = (const float*)d_in[14];
    const float* bout = (const float*)d_in[15];
    const int*   eidx = (const int*)d_in[16];

    const int N = in_sizes[0];          // x is [N,1]  (100000 -> src fits 17 bits)
    const int E = in_sizes[1];          // edge_weight is [E]
    const int* src = eidx;              // edge_index[0]
    const int* dst = eidx + E;          // edge_index[1]

    const int nr = (N + RANGE - 1) / RANGE;          // 392 ranges
    // dense segment capacity: mean + 8 sigma, even (16B-aligned pairs)
    const int mean = E / nr;
    int capr = mean + 8 * (int)sqrtf((float)mean) + 16;
    capr = (capr + 1) & ~1;

    // Workspace (~15 MB of the 256 MiB d_ws):
    uint2* comp  = (uint2*)d_ws;                               // nr*capr
    int*   rcur  = (int*)(comp + (size_t)nr * capr);           // nr
    float* dinv  = (float*)(rcur + NRMAX);                     // N
    float* w     = dinv + N;                                   // N
    float* coeff = w + N;                                      // 4*HIDDEN

    // run cursors must start at 0 (workspace arrives poisoned)
    hipMemsetAsync(rcur, 0, NRMAX * sizeof(int), stream);

    k_part<<<NP, 512, 0, stream>>>(dst, src, ew, comp, rcur,
                                   Wz, bz, Lz, lbz, Wh, bh, Lh, lbh,
                                   coeff, E, nr, capr);
    k_degw<<<nr, 512, 0, stream>>>(comp, rcur, x, dinv, w, N, capr);
    k_aggout<<<nr, 512, 0, stream>>>(comp, rcur, w, dinv, coeff, Wout, bout,
                                     (float*)d_out, N, capr);
}